// Round 3
// baseline (1036.873 us; speedup 1.0000x reference)
//
#include <hip/hip_runtime.h>
#include <hip/hip_bf16.h>

// Problem constants
#define N_ANCH   589824     // 256*256*9
#define NBLK     2304       // N_ANCH / 256
#define TOPK     12000
#define KPAD     12032      // 188*64
#define NW       188        // mask words per row
#define OUTN     2000
#define CAP      32768      // candidate buffer capacity
#define NBIN     65536      // 16-bit prefix histogram

typedef unsigned long long u64;

// 9 base anchors (ratio-major, scale-minor), widths/heights (x1-x0+1)
__constant__ float c_aw[9] = {184.f, 368.f, 736.f, 128.f, 256.f, 512.f,  88.f, 176.f, 352.f};
__constant__ float c_ah[9] = { 96.f, 192.f, 384.f, 128.f, 256.f, 512.f, 176.f, 352.f, 704.f};

// Decode one anchor's proposal box exactly like the (non-fused fp32) reference.
__device__ __forceinline__ void decode_one(int i, const float4* __restrict__ delta,
                                           float4* box, bool* valid) {
#pragma clang fp contract(off)
    int a    = i % 9;
    int cell = i / 9;
    int gx = cell & 255;
    int gy = cell >> 8;
    float w = c_aw[a], h = c_ah[a];
    float cx = (float)gx * 16.0f + 8.0f;
    float cy = (float)gy * 16.0f + 8.0f;
    float4 d = delta[i];
    float pcx = d.x * w + cx;
    float pcy = d.y * h + cy;
    float pw  = expf(d.z) * w;
    float ph  = expf(d.w) * h;
    float x0 = fminf(fmaxf(pcx - 0.5f * pw, 0.f), 4096.f);
    float y0 = fminf(fmaxf(pcy - 0.5f * ph, 0.f), 4096.f);
    float x1 = fminf(fmaxf(pcx + 0.5f * pw, 0.f), 4096.f);
    float y1 = fminf(fmaxf(pcy + 0.5f * ph, 0.f), 4096.f);
    *box = make_float4(x0, y0, x1, y1);
    *valid = (x1 - x0 >= 16.f) && (y1 - y0 >= 16.f);
}

// Decode + key + 16-bit global histogram; last block computes threshold P.
// ctrl: [0]=P, [3]=cand count (written later), [8]=done counter.
__global__ __launch_bounds__(256) void k_score(const float4* __restrict__ delta,
                                               const float2* __restrict__ score,
                                               unsigned* __restrict__ ukey,
                                               unsigned* __restrict__ hist,
                                               unsigned* __restrict__ ctrl) {
    int tid = threadIdx.x;
    int i = blockIdx.x * 256 + tid;
    float4 box; bool valid;
    decode_one(i, delta, &box, &valid);
    unsigned u = 0u;
    if (valid) {
        unsigned b = __float_as_uint(score[i].y);
        u = (b & 0x80000000u) ? ~b : (b | 0x80000000u);  // order-preserving; 0 = dead
    }
    ukey[i] = u;
    atomicAdd(&hist[u >> 16], 1u);

    // last-block-done: the final block scans the histogram for threshold P
    __shared__ int lastf;
    __threadfence();
    __syncthreads();
    if (tid == 0) lastf = (atomicAdd(&ctrl[8], 1u) == (unsigned)(gridDim.x - 1)) ? 1 : 0;
    __syncthreads();
    if (!lastf) return;

    __shared__ unsigned ss[256];
    __shared__ int sc;
    unsigned csum = 0;
    const unsigned* hb = hist + tid * 256;
    #pragma unroll 8
    for (int k = 0; k < 256; ++k) csum += hb[k];
    ss[tid] = csum;
    if (tid == 0) sc = -1;
    __syncthreads();
    for (int d = 1; d < 256; d <<= 1) {           // suffix scan over chunk sums
        unsigned v = (tid + d < 256) ? ss[tid + d] : 0u;
        __syncthreads();
        ss[tid] += v;
        __syncthreads();
    }
    unsigned nextS = (tid + 1 < 256) ? ss[tid + 1] : 0u;
    if (ss[tid] >= (unsigned)TOPK && nextS < (unsigned)TOPK) sc = tid;
    __syncthreads();
    if (tid == 0) {
        unsigned P = 0;
        int c = sc;
        if (c >= 0) {
            unsigned acc = (c + 1 < 256) ? ss[c + 1] : 0u;
            int b = 255;
            for (; b > 0; --b) {
                acc += hist[c * 256 + b];
                if (acc >= (unsigned)TOPK) break;
            }
            P = (unsigned)(c * 256 + b);
        }
        ctrl[0] = P;
    }
}

// Compact all items with prefix >= P (and alive) into candidate list.
__global__ __launch_bounds__(256) void k_compact(const unsigned* __restrict__ ukey,
                                                 const unsigned* __restrict__ ctrl,
                                                 unsigned* __restrict__ cnt,
                                                 u64* __restrict__ cand) {
    unsigned P = ctrl[0];
    int i = blockIdx.x * 256 + threadIdx.x;
    unsigned u = ukey[i];
    bool pred = (u != 0u) && ((u >> 16) >= P);
    u64 m = __ballot(pred);
    if (m == 0ull) return;
    int lane = threadIdx.x & 63;
    int leader = __ffsll(m) - 1;
    unsigned base = 0;
    if (lane == leader) base = atomicAdd(cnt, (unsigned)__popcll(m));
    base = __shfl(base, leader);
    if (pred) {
        u64 below = m & ((1ull << lane) - 1ull);
        unsigned pos = base + (unsigned)__popcll(below);
        if (pos < CAP) cand[pos] = ((u64)u << 32) | (unsigned)(~i);
    }
}

// Exact rank (desc score, asc index) + direct decode of top-K boxes into sbox.
__global__ __launch_bounds__(256) void k_rankdec(const u64* __restrict__ cand,
                                                 const unsigned* __restrict__ ctrl,
                                                 const float4* __restrict__ delta,
                                                 float4* __restrict__ sboxes) {
    unsigned cnt = ctrl[3];
    int C = (int)(cnt < (unsigned)CAP ? cnt : (unsigned)CAP);
    if ((int)(blockIdx.x * 256) >= C) return;
    int t = blockIdx.x * 256 + threadIdx.x;
    u64 mykey = (t < C) ? cand[t] : ~0ull;
    int rank = 0;
    __shared__ u64 tile[256];
    for (int j0 = 0; j0 < C; j0 += 256) {
        int j = j0 + threadIdx.x;
        tile[threadIdx.x] = (j < C) ? cand[j] : 0ull;
        __syncthreads();
        int lim = (C - j0 < 256) ? (C - j0) : 256;
        #pragma unroll 4
        for (int jj = 0; jj < lim; ++jj) rank += (tile[jj] > mykey) ? 1 : 0;
        __syncthreads();
    }
    if (t < C && rank < TOPK) {
        int idx = (int)(~(unsigned)mykey);
        float4 box; bool v;
        decode_one(idx, delta, &box, &v);
        sboxes[rank] = box;
    }
}

// Suppression bitmask: bit j of mask[r][cb] set iff IoU(r, cb*64+j) > 0.7 and j != r.
// Only upper triangle (cb >= rb) computed; k_reduce only reads words t >= row's block.
__global__ __launch_bounds__(64) void k_mask(const float4* __restrict__ sboxes,
                                             u64* __restrict__ mask) {
    int cb = blockIdx.x, rb = blockIdx.y;
    if (cb < rb) return;
    __shared__ float4 cbox[64];
    int tid = threadIdx.x;
    cbox[tid] = sboxes[cb * 64 + tid];
    __syncthreads();
    int r = rb * 64 + tid;
    float4 me = sboxes[r];
    float areaMe = (me.z - me.x) * (me.w - me.y);
    u64 bits = 0ull;
    for (int j = 0; j < 64; ++j) {
        float4 o = cbox[j];
        float xx0 = fmaxf(me.x, o.x);
        float yy0 = fmaxf(me.y, o.y);
        float xx1 = fminf(me.z, o.z);
        float yy1 = fminf(me.w, o.w);
        float iw = fmaxf(xx1 - xx0, 0.f);
        float ih = fmaxf(yy1 - yy0, 0.f);
        float inter = iw * ih;
        float areaO = (o.z - o.x) * (o.w - o.y);
        float denom = fmaxf(areaMe + areaO - inter, 1e-8f);
        float iou = inter / denom;
        if (iou > 0.7f && (cb * 64 + j) != r) bits |= (1ull << j);
    }
    mask[(size_t)r * NW + cb] = bits;
}

// Blocked greedy reduce, 256 threads: thread t exclusively owns column word t
// (register). Per 64-rank block: wave3 prefetches next diag tile, wave0 does the
// serial in-register resolve, all threads OR kept rows 8-deep-batched (one
// memory latency per block). Tail zero-fills the output.
__global__ __launch_bounds__(256) void k_reduce(const float4* __restrict__ sboxes,
                                                const unsigned* __restrict__ ctrl,
                                                const u64* __restrict__ mask,
                                                float4* __restrict__ out) {
    int t = threadIdx.x;
    int lane = t & 63;
    int wave = t >> 6;
    unsigned cnt = ctrl[3];
    int C = (int)(cnt < (unsigned)CAP ? cnt : (unsigned)CAP);
    int nvalid = C < TOPK ? C : TOPK;
    int nblocks = (nvalid + 63) >> 6;

    __shared__ u64 diag[2][64];
    __shared__ u64 s_rw;
    __shared__ unsigned s_rows[64];
    __shared__ int s_kc;
    __shared__ int s_nkept;

    // thread t owns removed word t (ranks [64t, 64t+64)); tail pre-removed
    u64 removed_t = ~0ull;
    if (t < NW) {
        long long lo = (long long)t * 64;
        if (lo + 64 <= (long long)nvalid) removed_t = 0ull;
        else if (lo < (long long)nvalid)
            removed_t = ~((1ull << (unsigned)(nvalid - lo)) - 1ull);
    }
    if (t == 0) s_nkept = 0;
    if (wave == 3 && nblocks > 0) diag[0][lane] = mask[(size_t)lane * NW + 0];
    __syncthreads();

    for (int b = 0; b < nblocks; ++b) {
        int cur = b & 1;
        if (wave == 3 && b + 1 < nblocks)
            diag[cur ^ 1][lane] = mask[(size_t)((b + 1) * 64 + lane) * NW + (b + 1)];
        if (t == b) s_rw = removed_t;
        __syncthreads();   // A: s_rw + diag[cur] ready

        if (wave == 0) {
            u64 dg = diag[cur][lane];
            u64 avail = ~s_rw;
            int nk = s_nkept;
            int budget = OUTN - nk;
            u64 keptmask = 0ull; int kc = 0;
            while (avail && kc < budget) {
                int j = __ffsll(avail) - 1;
                keptmask |= (1ull << j);
                ++kc;
                u64 dj = __shfl(dg, j);
                avail &= ~dj;
                avail &= ~(1ull << j);
            }
            if ((keptmask >> lane) & 1ull) {
                int p = (int)__popcll(keptmask & ((1ull << lane) - 1ull));
                s_rows[p] = (unsigned)(b * 64 + lane);
                out[nk + p] = sboxes[b * 64 + lane];
            }
            if (kc > 0) {   // pad row list to multiple of 8 (duplicate OR is idempotent)
                int r0 = b * 64 + (__ffsll(keptmask) - 1);
                int kcp = (kc + 7) & ~7;
                if (lane >= kc && lane < kcp) s_rows[lane] = (unsigned)r0;
            }
            if (lane == 0) { s_kc = kc; s_nkept = nk + kc; }
        }
        __syncthreads();   // B: s_rows/s_kc/s_nkept ready

        if (s_nkept >= OUTN) break;
        int kc = s_kc;
        if (kc > 0 && t < NW && t > b) {
            const u64* mt = mask + t;
            u64 acc = removed_t;
            int kcp = (kc + 7) & ~7;
            for (int i = 0; i < kcp; i += 8) {
                u64 a0 = mt[(size_t)s_rows[i + 0] * NW];
                u64 a1 = mt[(size_t)s_rows[i + 1] * NW];
                u64 a2 = mt[(size_t)s_rows[i + 2] * NW];
                u64 a3 = mt[(size_t)s_rows[i + 3] * NW];
                u64 a4 = mt[(size_t)s_rows[i + 4] * NW];
                u64 a5 = mt[(size_t)s_rows[i + 5] * NW];
                u64 a6 = mt[(size_t)s_rows[i + 6] * NW];
                u64 a7 = mt[(size_t)s_rows[i + 7] * NW];
                acc |= ((a0 | a1) | (a2 | a3)) | ((a4 | a5) | (a6 | a7));
            }
            removed_t = acc;
        }
        // next iteration's barrier A orders the t==b+1 publish after this OR
    }

    int nk = s_nkept;
    float4 z = make_float4(0.f, 0.f, 0.f, 0.f);
    for (int p = nk + t; p < OUTN; p += 256) out[p] = z;
}

extern "C" void kernel_launch(void* const* d_in, const int* in_sizes, int n_in,
                              void* d_out, int out_size, void* d_ws, size_t ws_size,
                              hipStream_t stream) {
    const float4* delta = (const float4*)d_in[0];
    const float2* score = (const float2*)d_in[1];
    char* ws = (char*)d_ws;

    // Workspace layout (bytes); cand aliases hist (disjoint lifetimes)
    unsigned* ukey = (unsigned*)(ws + 0);          // N_ANCH u32            [K1 -> K2]
    unsigned* hist = (unsigned*)(ws + 2359296);    // 65536 u32             [K1 only]
    u64*      cand = (u64*)(ws + 2359296);         // CAP u64 (alias hist)  [K2 -> K3]
    unsigned* ctrl = (unsigned*)(ws + 2621440);    // 16 u32
    float4*   sbox = (float4*)(ws + 2621504);      // KPAD float4           [K3 -> K5]
    u64*      mask = (u64*)(ws + 2814016);         // KPAD*NW u64           [K4 -> K5]

    hipMemsetAsync(ws + 2359296, 0, 262144 + 64, stream);   // hist + ctrl
    hipMemsetAsync(ws + 2621504, 0, 192512, stream);        // sbox (pad rows stay zero)

    k_score  <<<NBLK,     256, 0, stream>>>(delta, score, ukey, hist, ctrl);
    k_compact<<<NBLK,     256, 0, stream>>>(ukey, ctrl, ctrl + 3, cand);
    k_rankdec<<<CAP/256,  256, 0, stream>>>(cand, ctrl, delta, sbox);
    dim3 mgrid(NW, NW);
    k_mask   <<<mgrid,    64,  0, stream>>>(sbox, mask);
    k_reduce <<<1,        256, 0, stream>>>(sbox, ctrl, mask, (float4*)d_out);
}

// Round 4
// 985.147 us; speedup vs baseline: 1.0525x; 1.0525x over previous
//
#include <hip/hip_runtime.h>
#include <hip/hip_bf16.h>

// Problem constants
#define N_ANCH   589824     // 256*256*9
#define NBLK     2304       // N_ANCH / 256
#define TOPK     12000
#define KPAD     12032      // 188*64
#define NW       188        // mask words per row
#define OUTN     2000
#define CAP      32768      // candidate buffer capacity

typedef unsigned long long u64;

// 9 base anchors (ratio-major, scale-minor), widths/heights (x1-x0+1)
__constant__ float c_aw[9] = {184.f, 368.f, 736.f, 128.f, 256.f, 512.f,  88.f, 176.f, 352.f};
__constant__ float c_ah[9] = { 96.f, 192.f, 384.f, 128.f, 256.f, 512.f, 176.f, 352.f, 704.f};

// Decode one anchor's proposal box exactly like the (non-fused fp32) reference.
__device__ __forceinline__ void decode_one(int i, const float4* __restrict__ delta,
                                           float4* box, bool* valid) {
#pragma clang fp contract(off)
    int a    = i % 9;
    int cell = i / 9;
    int gx = cell & 255;
    int gy = cell >> 8;
    float w = c_aw[a], h = c_ah[a];
    float cx = (float)gx * 16.0f + 8.0f;
    float cy = (float)gy * 16.0f + 8.0f;
    float4 d = delta[i];
    float pcx = d.x * w + cx;
    float pcy = d.y * h + cy;
    float pw  = expf(d.z) * w;
    float ph  = expf(d.w) * h;
    float x0 = fminf(fmaxf(pcx - 0.5f * pw, 0.f), 4096.f);
    float y0 = fminf(fmaxf(pcy - 0.5f * ph, 0.f), 4096.f);
    float x1 = fminf(fmaxf(pcx + 0.5f * pw, 0.f), 4096.f);
    float y1 = fminf(fmaxf(pcy + 0.5f * ph, 0.f), 4096.f);
    *box = make_float4(x0, y0, x1, y1);
    *valid = (x1 - x0 >= 16.f) && (y1 - y0 >= 16.f);
}

// Decode + key + 16-bit global histogram. No fence: k_thresh is a separate dispatch.
__global__ __launch_bounds__(256) void k_score(const float4* __restrict__ delta,
                                               const float2* __restrict__ score,
                                               unsigned* __restrict__ ukey,
                                               unsigned* __restrict__ hist) {
    int i = blockIdx.x * 256 + threadIdx.x;
    float4 box; bool valid;
    decode_one(i, delta, &box, &valid);
    unsigned u = 0u;
    if (valid) {
        unsigned b = __float_as_uint(score[i].y);
        u = (b & 0x80000000u) ? ~b : (b | 0x80000000u);  // order-preserving; 0 = dead
    }
    ukey[i] = u;
    atomicAdd(&hist[u >> 16], 1u);
}

// Threshold scan: suffix-scan the 64K-bin histogram, find P s.t. count(prefix>=P) >= TOPK.
__global__ __launch_bounds__(1024) void k_thresh(const unsigned* __restrict__ hist,
                                                 unsigned* __restrict__ ctrl) {
    __shared__ unsigned ss[1024];
    __shared__ int sc;
    int tid = threadIdx.x;
    const uint4* hb = (const uint4*)hist + tid * 16;
    unsigned csum = 0;
    #pragma unroll
    for (int k = 0; k < 16; ++k) {
        uint4 h = hb[k];
        csum += h.x + h.y + h.z + h.w;
    }
    ss[tid] = csum;
    if (tid == 0) sc = -1;
    __syncthreads();
    for (int d = 1; d < 1024; d <<= 1) {          // suffix scan over 64-bin chunk sums
        unsigned v = (tid + d < 1024) ? ss[tid + d] : 0u;
        __syncthreads();
        ss[tid] += v;
        __syncthreads();
    }
    unsigned nextS = (tid + 1 < 1024) ? ss[tid + 1] : 0u;
    if (ss[tid] >= (unsigned)TOPK && nextS < (unsigned)TOPK) sc = tid;
    __syncthreads();
    if (tid == 0) {
        unsigned P = 0;
        int c = sc;
        if (c >= 0) {
            unsigned acc = (c + 1 < 1024) ? ss[c + 1] : 0u;
            int b = 63;
            for (; b > 0; --b) {
                acc += hist[c * 64 + b];
                if (acc >= (unsigned)TOPK) break;
            }
            P = (unsigned)(c * 64 + b);
        }
        ctrl[0] = P;
    }
}

// Compact all items with prefix >= P (and alive) into candidate list.
__global__ __launch_bounds__(256) void k_compact(const unsigned* __restrict__ ukey,
                                                 const unsigned* __restrict__ ctrl,
                                                 unsigned* __restrict__ cnt,
                                                 u64* __restrict__ cand) {
    unsigned P = ctrl[0];
    int i = blockIdx.x * 256 + threadIdx.x;
    unsigned u = ukey[i];
    bool pred = (u != 0u) && ((u >> 16) >= P);
    u64 m = __ballot(pred);
    if (m == 0ull) return;
    int lane = threadIdx.x & 63;
    int leader = __ffsll(m) - 1;
    unsigned base = 0;
    if (lane == leader) base = atomicAdd(cnt, (unsigned)__popcll(m));
    base = __shfl(base, leader);
    if (pred) {
        u64 below = m & ((1ull << lane) - 1ull);
        unsigned pos = base + (unsigned)__popcll(below);
        if (pos < CAP) cand[pos] = ((u64)u << 32) | (unsigned)(~i);
    }
}

// Exact rank (desc score, asc index) + direct decode of top-K boxes into sbox.
__global__ __launch_bounds__(256) void k_rankdec(const u64* __restrict__ cand,
                                                 const unsigned* __restrict__ ctrl,
                                                 const float4* __restrict__ delta,
                                                 float4* __restrict__ sboxes) {
    unsigned cnt = ctrl[3];
    int C = (int)(cnt < (unsigned)CAP ? cnt : (unsigned)CAP);
    if ((int)(blockIdx.x * 256) >= C) return;
    int t = blockIdx.x * 256 + threadIdx.x;
    u64 mykey = (t < C) ? cand[t] : ~0ull;
    int rank = 0;
    __shared__ u64 tile[256];
    for (int j0 = 0; j0 < C; j0 += 256) {
        int j = j0 + threadIdx.x;
        tile[threadIdx.x] = (j < C) ? cand[j] : 0ull;
        __syncthreads();
        int lim = (C - j0 < 256) ? (C - j0) : 256;
        #pragma unroll 4
        for (int jj = 0; jj < lim; ++jj) rank += (tile[jj] > mykey) ? 1 : 0;
        __syncthreads();
    }
    if (t < C && rank < TOPK) {
        int idx = (int)(~(unsigned)mykey);
        float4 box; bool v;
        decode_one(idx, delta, &box, &v);
        sboxes[rank] = box;
    }
}

// Suppression bitmask, 4 column-tiles per block. bit j of mask[r][cb] set iff
// IoU(r, cb*64+j) > 0.7 and j != r. Only upper triangle (cb >= rb) written/read.
__global__ __launch_bounds__(64) void k_mask(const float4* __restrict__ sboxes,
                                             u64* __restrict__ mask) {
    int rb = blockIdx.y;
    int cb0 = blockIdx.x * 4;
    if (cb0 + 3 < rb) return;
    int tid = threadIdx.x;
    int r = rb * 64 + tid;
    float4 me = sboxes[r];
    float areaMe = (me.z - me.x) * (me.w - me.y);
    __shared__ float4 cbox[64];
    for (int q = 0; q < 4; ++q) {                 // wave-uniform guard: 1-wave block
        int cb = cb0 + q;
        if (cb < rb) continue;
        __syncthreads();
        cbox[tid] = sboxes[cb * 64 + tid];
        __syncthreads();
        u64 bits = 0ull;
        for (int j = 0; j < 64; ++j) {
            float4 o = cbox[j];
            float xx0 = fmaxf(me.x, o.x);
            float yy0 = fmaxf(me.y, o.y);
            float xx1 = fminf(me.z, o.z);
            float yy1 = fminf(me.w, o.w);
            float iw = fmaxf(xx1 - xx0, 0.f);
            float ih = fmaxf(yy1 - yy0, 0.f);
            float inter = iw * ih;
            float areaO = (o.z - o.x) * (o.w - o.y);
            float denom = fmaxf(areaMe + areaO - inter, 1e-8f);
            float iou = inter / denom;
            if (iou > 0.7f && (cb * 64 + j) != r) bits |= (1ull << j);
        }
        mask[(size_t)r * NW + cb] = bits;
    }
}

// Blocked greedy reduce, 256 threads: thread t exclusively owns column word t
// (register). Per 64-rank block: wave3 prefetches next diag tile, wave0 does the
// serial in-register resolve, all threads OR kept rows 16-deep-batched (one
// memory latency per block typically). Tail zero-fills the output.
__global__ __launch_bounds__(256) void k_reduce(const float4* __restrict__ sboxes,
                                                const unsigned* __restrict__ ctrl,
                                                const u64* __restrict__ mask,
                                                float4* __restrict__ out) {
    int t = threadIdx.x;
    int lane = t & 63;
    int wave = t >> 6;
    unsigned cnt = ctrl[3];
    int C = (int)(cnt < (unsigned)CAP ? cnt : (unsigned)CAP);
    int nvalid = C < TOPK ? C : TOPK;
    int nblocks = (nvalid + 63) >> 6;

    __shared__ u64 diag[2][64];
    __shared__ u64 s_rw;
    __shared__ unsigned s_rows[64];
    __shared__ int s_kc;
    __shared__ int s_nkept;

    // thread t owns removed word t (ranks [64t, 64t+64)); tail pre-removed
    u64 removed_t = ~0ull;
    if (t < NW) {
        long long lo = (long long)t * 64;
        if (lo + 64 <= (long long)nvalid) removed_t = 0ull;
        else if (lo < (long long)nvalid)
            removed_t = ~((1ull << (unsigned)(nvalid - lo)) - 1ull);
    }
    if (t == 0) s_nkept = 0;
    if (wave == 3 && nblocks > 0) diag[0][lane] = mask[(size_t)lane * NW + 0];
    __syncthreads();

    for (int b = 0; b < nblocks; ++b) {
        int cur = b & 1;
        if (wave == 3 && b + 1 < nblocks)
            diag[cur ^ 1][lane] = mask[(size_t)((b + 1) * 64 + lane) * NW + (b + 1)];
        if (t == b) s_rw = removed_t;
        __syncthreads();   // A: s_rw + diag[cur] ready

        if (wave == 0) {
            u64 dg = diag[cur][lane];
            u64 avail = ~s_rw;
            int nk = s_nkept;
            int budget = OUTN - nk;
            u64 keptmask = 0ull; int kc = 0;
            while (avail && kc < budget) {
                int j = __ffsll(avail) - 1;
                keptmask |= (1ull << j);
                ++kc;
                u64 dj = __shfl(dg, j);
                avail &= ~dj;
                avail &= ~(1ull << j);
            }
            if ((keptmask >> lane) & 1ull) {
                int p = (int)__popcll(keptmask & ((1ull << lane) - 1ull));
                s_rows[p] = (unsigned)(b * 64 + lane);
                out[nk + p] = sboxes[b * 64 + lane];
            }
            if (kc > 0) {   // pad row list to multiple of 16 (duplicate OR idempotent)
                int r0 = b * 64 + (__ffsll(keptmask) - 1);
                int kcp = (kc + 15) & ~15;
                if (lane >= kc && lane < kcp) s_rows[lane] = (unsigned)r0;
            }
            if (lane == 0) { s_kc = kc; s_nkept = nk + kc; }
        }
        __syncthreads();   // B: s_rows/s_kc/s_nkept ready

        if (s_nkept >= OUTN) break;
        int kc = s_kc;
        if (kc > 0 && t < NW && t > b) {
            const u64* mt = mask + t;
            u64 acc = removed_t;
            int kcp = (kc + 15) & ~15;
            for (int i = 0; i < kcp; i += 16) {
                u64 a0  = mt[(size_t)s_rows[i + 0]  * NW];
                u64 a1  = mt[(size_t)s_rows[i + 1]  * NW];
                u64 a2  = mt[(size_t)s_rows[i + 2]  * NW];
                u64 a3  = mt[(size_t)s_rows[i + 3]  * NW];
                u64 a4  = mt[(size_t)s_rows[i + 4]  * NW];
                u64 a5  = mt[(size_t)s_rows[i + 5]  * NW];
                u64 a6  = mt[(size_t)s_rows[i + 6]  * NW];
                u64 a7  = mt[(size_t)s_rows[i + 7]  * NW];
                u64 a8  = mt[(size_t)s_rows[i + 8]  * NW];
                u64 a9  = mt[(size_t)s_rows[i + 9]  * NW];
                u64 a10 = mt[(size_t)s_rows[i + 10] * NW];
                u64 a11 = mt[(size_t)s_rows[i + 11] * NW];
                u64 a12 = mt[(size_t)s_rows[i + 12] * NW];
                u64 a13 = mt[(size_t)s_rows[i + 13] * NW];
                u64 a14 = mt[(size_t)s_rows[i + 14] * NW];
                u64 a15 = mt[(size_t)s_rows[i + 15] * NW];
                acc |= (((a0 | a1) | (a2 | a3)) | ((a4 | a5) | (a6 | a7)))
                     | (((a8 | a9) | (a10 | a11)) | ((a12 | a13) | (a14 | a15)));
            }
            removed_t = acc;
        }
        // next iteration's barrier A orders the t==b+1 publish after this OR
    }

    int nk = s_nkept;
    float4 z = make_float4(0.f, 0.f, 0.f, 0.f);
    for (int p = nk + t; p < OUTN; p += 256) out[p] = z;
}

extern "C" void kernel_launch(void* const* d_in, const int* in_sizes, int n_in,
                              void* d_out, int out_size, void* d_ws, size_t ws_size,
                              hipStream_t stream) {
    const float4* delta = (const float4*)d_in[0];
    const float2* score = (const float2*)d_in[1];
    char* ws = (char*)d_ws;

    // Workspace layout (bytes); cand aliases hist (disjoint lifetimes)
    unsigned* ukey = (unsigned*)(ws + 0);          // N_ANCH u32            [K1 -> K3]
    unsigned* hist = (unsigned*)(ws + 2359296);    // 65536 u32             [K1 -> K2]
    u64*      cand = (u64*)(ws + 2359296);         // CAP u64 (alias hist)  [K3 -> K4]
    unsigned* ctrl = (unsigned*)(ws + 2621440);    // 16 u32
    float4*   sbox = (float4*)(ws + 2621504);      // KPAD float4           [K4 -> K6]
    u64*      mask = (u64*)(ws + 2814016);         // KPAD*NW u64           [K5 -> K6]

    hipMemsetAsync(ws + 2359296, 0, 262144 + 64, stream);   // hist + ctrl
    hipMemsetAsync(ws + 2621504, 0, 192512, stream);        // sbox (pad rows stay zero)

    k_score  <<<NBLK,    256,  0, stream>>>(delta, score, ukey, hist);
    k_thresh <<<1,       1024, 0, stream>>>(hist, ctrl);
    k_compact<<<NBLK,    256,  0, stream>>>(ukey, ctrl, ctrl + 3, cand);
    k_rankdec<<<CAP/256, 256,  0, stream>>>(cand, ctrl, delta, sbox);
    dim3 mgrid(47, NW);
    k_mask   <<<mgrid,   64,   0, stream>>>(sbox, mask);
    k_reduce <<<1,       256,  0, stream>>>(sbox, ctrl, mask, (float4*)d_out);
}

// Round 6
// 891.044 us; speedup vs baseline: 1.1637x; 1.1056x over previous
//
#include <hip/hip_runtime.h>
#include <hip/hip_bf16.h>

// Problem constants
#define N_ANCH   589824     // 256*256*9
#define NBLK     2304       // N_ANCH / 256
#define TOPK     12000
#define KPAD     12032      // 188*64
#define NW       188        // mask words per row
#define OUTN     2000
#define CAP      32768      // candidate buffer capacity

typedef unsigned long long u64;

// 9 base anchors (ratio-major, scale-minor), widths/heights (x1-x0+1)
__constant__ float c_aw[9] = {184.f, 368.f, 736.f, 128.f, 256.f, 512.f,  88.f, 176.f, 352.f};
__constant__ float c_ah[9] = { 96.f, 192.f, 384.f, 128.f, 256.f, 512.f, 176.f, 352.f, 704.f};

// Decode one anchor's proposal box exactly like the (non-fused fp32) reference.
__device__ __forceinline__ void decode_one(int i, const float4* __restrict__ delta,
                                           float4* box, bool* valid) {
#pragma clang fp contract(off)
    int a    = i % 9;
    int cell = i / 9;
    int gx = cell & 255;
    int gy = cell >> 8;
    float w = c_aw[a], h = c_ah[a];
    float cx = (float)gx * 16.0f + 8.0f;
    float cy = (float)gy * 16.0f + 8.0f;
    float4 d = delta[i];
    float pcx = d.x * w + cx;
    float pcy = d.y * h + cy;
    float pw  = expf(d.z) * w;
    float ph  = expf(d.w) * h;
    float x0 = fminf(fmaxf(pcx - 0.5f * pw, 0.f), 4096.f);
    float y0 = fminf(fmaxf(pcy - 0.5f * ph, 0.f), 4096.f);
    float x1 = fminf(fmaxf(pcx + 0.5f * pw, 0.f), 4096.f);
    float y1 = fminf(fmaxf(pcy + 0.5f * ph, 0.f), 4096.f);
    *box = make_float4(x0, y0, x1, y1);
    *valid = (x1 - x0 >= 16.f) && (y1 - y0 >= 16.f);
}

// Decode + key + LDS-aggregated level-1 histogram (bits 31:24).
__global__ __launch_bounds__(256) void k_score(const float4* __restrict__ delta,
                                               const float2* __restrict__ score,
                                               unsigned* __restrict__ ukey,
                                               unsigned* __restrict__ hist1) {
    __shared__ unsigned lh[256];
    int tid = threadIdx.x;
    lh[tid] = 0u;
    __syncthreads();
    int i = blockIdx.x * 256 + tid;
    float4 box; bool valid;
    decode_one(i, delta, &box, &valid);
    unsigned u = 0u;
    if (valid) {
        unsigned b = __float_as_uint(score[i].y);
        u = (b & 0x80000000u) ? ~b : (b | 0x80000000u);  // order-preserving; 0 = dead
    }
    ukey[i] = u;
    atomicAdd(&lh[u >> 24], 1u);
    __syncthreads();
    unsigned c = lh[tid];
    if (c) atomicAdd(&hist1[tid], c);
}

// Level-2 histogram (bits 23:16 of items in bucket b1). Each block redundantly
// computes b1 from hist1 via an LDS suffix scan (no separate scan dispatch).
__global__ __launch_bounds__(256) void k_hist2(const unsigned* __restrict__ ukey,
                                               const unsigned* __restrict__ hist1,
                                               unsigned* __restrict__ hist2) {
    __shared__ unsigned ss[256];
    __shared__ unsigned lh[256];
    __shared__ unsigned s_b1;
    int tid = threadIdx.x;
    ss[tid] = hist1[tid];
    lh[tid] = 0u;
    if (tid == 0) s_b1 = 0u;
    __syncthreads();
    for (int d = 1; d < 256; d <<= 1) {       // suffix scan
        unsigned v = (tid + d < 256) ? ss[tid + d] : 0u;
        __syncthreads();
        ss[tid] += v;
        __syncthreads();
    }
    if (ss[tid] >= (unsigned)TOPK && (tid == 255 || ss[tid + 1] < (unsigned)TOPK))
        s_b1 = (unsigned)tid;                 // unique crossing (suffix monotone)
    __syncthreads();
    unsigned b1 = s_b1;
    int i = blockIdx.x * 256 + tid;
    unsigned u = ukey[i];
    if ((u >> 24) == b1) atomicAdd(&lh[(u >> 16) & 255u], 1u);
    __syncthreads();
    unsigned c = lh[tid];
    if (c) atomicAdd(&hist2[tid], c);
}

// Compact items with 16-bit prefix >= P. Each block redundantly recomputes
// P = (b1<<8)|b2 from hist1+hist2 (two LDS suffix scans).
__global__ __launch_bounds__(256) void k_compact(const unsigned* __restrict__ ukey,
                                                 const unsigned* __restrict__ hist1,
                                                 const unsigned* __restrict__ hist2,
                                                 unsigned* __restrict__ cnt,
                                                 u64* __restrict__ cand) {
    __shared__ unsigned ss[256];
    __shared__ unsigned s_b1, s_ab1, s_P;
    int tid = threadIdx.x;
    ss[tid] = hist1[tid];
    if (tid == 0) { s_b1 = 0u; s_ab1 = 0u; }
    __syncthreads();
    for (int d = 1; d < 256; d <<= 1) {
        unsigned v = (tid + d < 256) ? ss[tid + d] : 0u;
        __syncthreads();
        ss[tid] += v;
        __syncthreads();
    }
    if (ss[tid] >= (unsigned)TOPK && (tid == 255 || ss[tid + 1] < (unsigned)TOPK)) {
        s_b1 = (unsigned)tid;
        s_ab1 = (tid == 255) ? 0u : ss[tid + 1];
    }
    __syncthreads();
    unsigned b1 = s_b1, ab1 = s_ab1;
    ss[tid] = hist2[tid];
    if (tid == 0) s_P = (b1 << 8);            // default b2 = 0 (take-all fallback)
    __syncthreads();
    for (int d = 1; d < 256; d <<= 1) {
        unsigned v = (tid + d < 256) ? ss[tid + d] : 0u;
        __syncthreads();
        ss[tid] += v;
        __syncthreads();
    }
    unsigned target = (unsigned)TOPK - ab1;
    if (ss[tid] >= target && (tid == 255 || ss[tid + 1] < target))
        s_P = (b1 << 8) | (unsigned)tid;
    __syncthreads();
    unsigned P = s_P;

    int i = blockIdx.x * 256 + tid;
    unsigned u = ukey[i];
    bool pred = (u != 0u) && ((u >> 16) >= P);
    u64 m = __ballot(pred);
    if (m == 0ull) return;
    int lane = tid & 63;
    int leader = __ffsll(m) - 1;
    unsigned base = 0;
    if (lane == leader) base = atomicAdd(cnt, (unsigned)__popcll(m));
    base = __shfl(base, leader);
    if (pred) {
        u64 below = m & ((1ull << lane) - 1ull);
        unsigned pos = base + (unsigned)__popcll(below);
        if (pos < CAP) cand[pos] = ((u64)u << 32) | (unsigned)(~i);
    }
}

// Exact rank (desc score, asc index) + direct decode of top-K boxes into sbox.
__global__ __launch_bounds__(256) void k_rankdec(const u64* __restrict__ cand,
                                                 const unsigned* __restrict__ ctrl,
                                                 const float4* __restrict__ delta,
                                                 float4* __restrict__ sboxes) {
    unsigned cnt = ctrl[3];
    int C = (int)(cnt < (unsigned)CAP ? cnt : (unsigned)CAP);
    if ((int)(blockIdx.x * 256) >= C) return;
    int t = blockIdx.x * 256 + threadIdx.x;
    u64 mykey = (t < C) ? cand[t] : ~0ull;
    int rank = 0;
    __shared__ u64 tile[256];
    for (int j0 = 0; j0 < C; j0 += 256) {
        int j = j0 + threadIdx.x;
        tile[threadIdx.x] = (j < C) ? cand[j] : 0ull;
        __syncthreads();
        int lim = (C - j0 < 256) ? (C - j0) : 256;
        #pragma unroll 4
        for (int jj = 0; jj < lim; ++jj) rank += (tile[jj] > mykey) ? 1 : 0;
        __syncthreads();
    }
    if (t < C && rank < TOPK) {
        int idx = (int)(~(unsigned)mykey);
        float4 box; bool v;
        decode_one(idx, delta, &box, &v);
        sboxes[rank] = box;
    }
}

// Suppression bitmask, COLUMN-MAJOR: mcol[cb*KPAD + r] bit j = IoU(r, cb*64+j)>0.7
// && j != r. Wave stores are 512B contiguous (coalesced). Upper triangle only.
__global__ __launch_bounds__(64) void k_mask(const float4* __restrict__ sboxes,
                                             u64* __restrict__ mcol) {
    int rb = blockIdx.y;
    int cb0 = blockIdx.x * 4;
    if (cb0 + 3 < rb) return;
    int tid = threadIdx.x;
    int r = rb * 64 + tid;
    float4 me = sboxes[r];
    float areaMe = (me.z - me.x) * (me.w - me.y);
    __shared__ float4 cbox[64];
    for (int q = 0; q < 4; ++q) {                 // wave-uniform guard: 1-wave block
        int cb = cb0 + q;
        if (cb < rb) continue;
        __syncthreads();
        cbox[tid] = sboxes[cb * 64 + tid];
        __syncthreads();
        u64 bits = 0ull;
        for (int j = 0; j < 64; ++j) {
            float4 o = cbox[j];
            float xx0 = fmaxf(me.x, o.x);
            float yy0 = fmaxf(me.y, o.y);
            float xx1 = fminf(me.z, o.z);
            float yy1 = fminf(me.w, o.w);
            float iw = fmaxf(xx1 - xx0, 0.f);
            float ih = fmaxf(yy1 - yy0, 0.f);
            float inter = iw * ih;
            float areaO = (o.z - o.x) * (o.w - o.y);
            float denom = fmaxf(areaMe + areaO - inter, 1e-8f);
            float iou = inter / denom;
            if (iou > 0.7f && (cb * 64 + j) != r) bits |= (1ull << j);
        }
        mcol[(size_t)cb * KPAD + r] = bits;
    }
}

// Blocked greedy reduce, 256 threads, ONE barrier per 64-rank block.
// - resolve: IoU symmetry => lane l tests bit j of ITS OWN diag word; pure
//   ballot + ffs, no cross-lane data movement (uniform across all 4 waves).
// - removed bitmap: thread t owns column word t in a register.
// - OR phase: 16 loads issued at iteration end, folded at next iteration start
//   (latency hidden under publish+barrier+resolve).
__global__ __launch_bounds__(256) void k_reduce(const float4* __restrict__ sboxes,
                                                const unsigned* __restrict__ ctrl,
                                                const u64* __restrict__ mcol,
                                                float4* __restrict__ out) {
    int t = threadIdx.x;
    int lane = t & 63;
    int wave = t >> 6;
    unsigned cnt = ctrl[3];
    int C = (int)(cnt < (unsigned)CAP ? cnt : (unsigned)CAP);
    int nvalid = C < TOPK ? C : TOPK;
    int nblocks = (nvalid + 63) >> 6;

    __shared__ u64 s_rw[2];

    u64 removed_t = ~0ull;                       // thread t owns word t
    if (t < NW) {
        long long lo = (long long)t * 64;
        if (lo + 64 <= (long long)nvalid) removed_t = 0ull;
        else if (lo < (long long)nvalid)
            removed_t = ~((1ull << (unsigned)(nvalid - lo)) - 1ull);
    }

    int nk = 0;
    u64 p0=0,p1=0,p2=0,p3=0,p4=0,p5=0,p6=0,p7=0;
    u64 p8=0,p9=0,p10=0,p11=0,p12=0,p13=0,p14=0,p15=0;
    u64 dgnext = 0ull;
    if (nblocks > 0) dgnext = mcol[(size_t)0 * KPAD + lane];   // diag block 0

    for (int b = 0; b < nblocks; ++b) {
        // fold pending ORs (issued last iteration)
        removed_t |= ((p0|p1)|(p2|p3)) | ((p4|p5)|(p6|p7));
        removed_t |= ((p8|p9)|(p10|p11)) | ((p12|p13)|(p14|p15));
        p0=p1=p2=p3=p4=p5=p6=p7=0ull;
        p8=p9=p10=p11=p12=p13=p14=p15=0ull;
        u64 dg = dgnext;
        if (t == b) s_rw[b & 1] = removed_t;     // word b now final
        __syncthreads();
        u64 rw = s_rw[b & 1];
        if (b + 1 < nblocks)                     // prefetch next diag (regs, all waves)
            dgnext = mcol[(size_t)(b + 1) * KPAD + (size_t)(b + 1) * 64 + lane];

        // resolve (identical/uniform in every wave)
        bool alive = ((rw >> lane) & 1ull) == 0ull;
        int budget = OUTN - nk;
        u64 keptmask = 0ull;
        int kc = 0;
        while (kc < budget) {
            u64 m = __ballot(alive);
            if (!m) break;
            int j = __ffsll(m) - 1;              // uniform
            keptmask |= (1ull << j);
            ++kc;
            alive = alive && (lane != j) && (((dg >> j) & 1ull) == 0ull);
        }

        if (wave == 0 && ((keptmask >> lane) & 1ull)) {
            int pos = nk + (int)__popcll(keptmask & ((1ull << lane) - 1ull));
            out[pos] = sboxes[b * 64 + lane];
        }
        nk += kc;
        if (nk >= OUTN) break;

        // issue pending ORs for next-iteration fold
        if (kc > 0 && t > b && t < NW) {
            const u64* colp = mcol + (size_t)t * KPAD + (size_t)b * 64;
            u64 km = keptmask;
            int jf = __ffsll(km) - 1;
            int i0 = jf;                          km &= km - 1;
            int i1  = km ? __ffsll(km) - 1 : jf;  km &= km - 1;
            int i2  = km ? __ffsll(km) - 1 : jf;  km &= km - 1;
            int i3  = km ? __ffsll(km) - 1 : jf;  km &= km - 1;
            int i4  = km ? __ffsll(km) - 1 : jf;  km &= km - 1;
            int i5  = km ? __ffsll(km) - 1 : jf;  km &= km - 1;
            int i6  = km ? __ffsll(km) - 1 : jf;  km &= km - 1;
            int i7  = km ? __ffsll(km) - 1 : jf;  km &= km - 1;
            int i8  = km ? __ffsll(km) - 1 : jf;  km &= km - 1;
            int i9  = km ? __ffsll(km) - 1 : jf;  km &= km - 1;
            int i10 = km ? __ffsll(km) - 1 : jf;  km &= km - 1;
            int i11 = km ? __ffsll(km) - 1 : jf;  km &= km - 1;
            int i12 = km ? __ffsll(km) - 1 : jf;  km &= km - 1;
            int i13 = km ? __ffsll(km) - 1 : jf;  km &= km - 1;
            int i14 = km ? __ffsll(km) - 1 : jf;  km &= km - 1;
            int i15 = km ? __ffsll(km) - 1 : jf;  km &= km - 1;
            p0 = colp[i0];   p1 = colp[i1];   p2 = colp[i2];   p3 = colp[i3];
            p4 = colp[i4];   p5 = colp[i5];   p6 = colp[i6];   p7 = colp[i7];
            p8 = colp[i8];   p9 = colp[i9];   p10 = colp[i10]; p11 = colp[i11];
            p12 = colp[i12]; p13 = colp[i13]; p14 = colp[i14]; p15 = colp[i15];
            while (km) {                          // rare: kc > 16
                int j = __ffsll(km) - 1; km &= km - 1;
                removed_t |= colp[j];
            }
        }
    }

    float4 z = make_float4(0.f, 0.f, 0.f, 0.f);
    for (int p = nk + t; p < OUTN; p += 256) out[p] = z;
}

extern "C" void kernel_launch(void* const* d_in, const int* in_sizes, int n_in,
                              void* d_out, int out_size, void* d_ws, size_t ws_size,
                              hipStream_t stream) {
    const float4* delta = (const float4*)d_in[0];
    const float2* score = (const float2*)d_in[1];
    char* ws = (char*)d_ws;

    // Workspace layout (bytes)
    unsigned* ukey  = (unsigned*)(ws + 0);         // N_ANCH u32, K1->K3
    u64*      cand  = (u64*)(ws + 2359296);        // CAP u64, K3->K4
    unsigned* hist1 = (unsigned*)(ws + 2621440);   // 256 u32 (memset region start)
    unsigned* hist2 = (unsigned*)(ws + 2622464);   // 256 u32
    unsigned* ctrl  = (unsigned*)(ws + 2623488);   // 16 u32
    float4*   sbox  = (float4*)(ws + 2623552);     // KPAD float4, K4->K6
    u64*      mcol  = (u64*)(ws + 2816064);        // NW*KPAD u64 col-major, K5->K6

    hipMemsetAsync(ws + 2621440, 0, 194624, stream);   // hist1+hist2+ctrl+sbox

    k_score  <<<NBLK,    256, 0, stream>>>(delta, score, ukey, hist1);
    k_hist2  <<<NBLK,    256, 0, stream>>>(ukey, hist1, hist2);
    k_compact<<<NBLK,    256, 0, stream>>>(ukey, hist1, hist2, ctrl + 3, cand);
    k_rankdec<<<CAP/256, 256, 0, stream>>>(cand, ctrl, delta, sbox);
    dim3 mgrid(47, NW);
    k_mask   <<<mgrid,   64,  0, stream>>>(sbox, mcol);
    k_reduce <<<1,       256, 0, stream>>>(sbox, ctrl, mcol, (float4*)d_out);
}